// Round 9
// baseline (87.480 us; speedup 1.0000x reference)
//
#include <hip/hip_runtime.h>
#include <hip/hip_fp16.h>
#include <hip/hip_cooperative_groups.h>

namespace cg = cooperative_groups;

#define IN_F   4096
#define OUT_F  4096
#define BATCH  32
#define NGPR   512          // groups per output row
#define BN     16           // output rows per block
#define NW     8            // waves per block
#define QPITCH 1540         // dwords per q-row in LDS (1536 + 4; 1540%32==4 -> 2-way banks)
#define NPITCH 516          // floats per norm-row in LDS (512 + 4)

typedef float f32x4  __attribute__((ext_vector_type(4)));
typedef short short8 __attribute__((ext_vector_type(8)));

__device__ __forceinline__ unsigned short f2bf_u(float f) {
    return __builtin_bit_cast(unsigned short, (__bf16)f);   // RNE via v_cvt
}

__device__ __forceinline__ void gload16(const void* gsrc, void* lds) {
    __builtin_amdgcn_global_load_lds(
        (const __attribute__((address_space(1))) void*)gsrc,
        (__attribute__((address_space(3))) void*)lds, 16, 0, 0);
}

// pack one A-fragment unit u (0..16383):
// apk unit u = (a*128 + s)*64 + q*16 + cl  holds bf16 x[a*16+cl][s*32+q*8 .. +8]
__device__ __forceinline__ void pack_unit(const float* __restrict__ x,
                                          unsigned short* __restrict__ apk, int u)
{
    const int row = u >> 9;          // 0..31
    const int c   = u & 511;         // 8-float chunk within row
    const float4 lo = *reinterpret_cast<const float4*>(&x[row * IN_F + c * 8]);
    const float4 hi = *reinterpret_cast<const float4*>(&x[row * IN_F + c * 8 + 4]);
    union { unsigned short us[8]; uint4 v; } pk;
    pk.us[0] = f2bf_u(lo.x); pk.us[1] = f2bf_u(lo.y);
    pk.us[2] = f2bf_u(lo.z); pk.us[3] = f2bf_u(lo.w);
    pk.us[4] = f2bf_u(hi.x); pk.us[5] = f2bf_u(hi.y);
    pk.us[6] = f2bf_u(hi.z); pk.us[7] = f2bf_u(hi.w);
    const int a = row >> 4, cl = row & 15, s = c >> 2, q = c & 3;
    const int unit = (a * 128 + s) * 64 + q * 16 + cl;
    *reinterpret_cast<uint4*>(&apk[unit * 8]) = pk.v;
}

__global__ __launch_bounds__(256)
void pack_x_kernel(const float* __restrict__ x, unsigned short* __restrict__ apk)
{
    pack_unit(x, apk, blockIdx.x * 256 + threadIdx.x);
}

// ---- main body (r7, verified): shared by cooperative and fallback paths ----
__device__ __forceinline__
void l3b_body(const float* __restrict__ x,
              const int* __restrict__ wq3,
              const void* __restrict__ wnorm_raw,
              const float* __restrict__ bias,
              float* __restrict__ out,
              const unsigned short* __restrict__ apk,
              unsigned int* qls, float (*nrm)[NPITCH], float (*red)[BATCH][17])
{
    const int tid   = threadIdx.x;
    const int w     = tid >> 6;
    const int lane  = tid & 63;
    const int nbase = blockIdx.x * BN;

    const int q  = lane >> 4;   // 0..3
    const int cl = lane & 15;   // 0..15

    // ---- weight_norm dtype probe (deterministic, wave-uniform) ----
    // 0 = float32, 1 = float16 (raw), 2 = bfloat16
    const unsigned short* wn16  = (const unsigned short*)wnorm_raw;
    const float*          wn32  = (const float*)wnorm_raw;
    const unsigned int*   wnu32 = (const unsigned int*)wnorm_raw;
    int mode;
    {
        const unsigned short h = wn16[lane];
        const float v16 = __half2float(__builtin_bit_cast(__half, h));
        const float vbf = __builtin_bit_cast(float, (unsigned int)h << 16);
        const float v32 = wn32[lane];
        const int c16 = __popcll(__ballot(v16 > 0.0095f && v16 < 1.0005f));
        const int cbf = __popcll(__ballot(vbf > 0.0095f && vbf < 1.0005f));
        const int c32 = __popcll(__ballot(v32 > 0.0095f && v32 < 1.0005f));
        if (c16 >= c32 && c16 >= cbf) {
            mode = 1;
        } else if (c32 > cbf + 8) {
            mode = 0;
        } else if (cbf > c32 + 8) {
            mode = 2;
        } else {
            const int z = __popcll(__ballot((wnu32[lane] & 0x1FFFu) == 0u));
            mode = (z >= 48) ? 0 : 2;
        }
    }

    // ---- stage raw q panel (16 rows x 1536 dwords, contiguous in global) ----
    {
        const int* qg = wq3 + (long)nbase * 1536;
        #pragma unroll
        for (int rr = 0; rr < 2; ++rr) {
            const int row = w * 2 + rr;
            #pragma unroll
            for (int i = 0; i < 6; ++i) {
                const int off = i * 256 + lane * 4;
                gload16(qg + (long)row * 1536 + off, &qls[row * QPITCH + off]);
            }
        }
    }

    // ---- stage norms -> fp32 LDS (rows contiguous in global, dense) ----
    if (mode == 0) {
        const float* nb = wn32 + (long)nbase * NGPR;
        #pragma unroll
        for (int j = 0; j < 4; ++j) {
            const int f = j * 2048 + tid * 4;
            const float4 v = *reinterpret_cast<const float4*>(nb + f);
            *reinterpret_cast<float4*>(&nrm[f >> 9][f & 511]) = v;
        }
    } else {
        const unsigned short* nb = wn16 + (long)nbase * NGPR;
        #pragma unroll
        for (int j = 0; j < 2; ++j) {
            const int f = j * 4096 + tid * 8;
            union { unsigned short us[8]; uint4 v; } u;
            u.v = *reinterpret_cast<const uint4*>(nb + f);
            float4 f0, f1;
            if (mode == 1) {
                f0.x = __half2float(__builtin_bit_cast(__half, u.us[0]));
                f0.y = __half2float(__builtin_bit_cast(__half, u.us[1]));
                f0.z = __half2float(__builtin_bit_cast(__half, u.us[2]));
                f0.w = __half2float(__builtin_bit_cast(__half, u.us[3]));
                f1.x = __half2float(__builtin_bit_cast(__half, u.us[4]));
                f1.y = __half2float(__builtin_bit_cast(__half, u.us[5]));
                f1.z = __half2float(__builtin_bit_cast(__half, u.us[6]));
                f1.w = __half2float(__builtin_bit_cast(__half, u.us[7]));
            } else {
                f0.x = __builtin_bit_cast(float, (unsigned)u.us[0] << 16);
                f0.y = __builtin_bit_cast(float, (unsigned)u.us[1] << 16);
                f0.z = __builtin_bit_cast(float, (unsigned)u.us[2] << 16);
                f0.w = __builtin_bit_cast(float, (unsigned)u.us[3] << 16);
                f1.x = __builtin_bit_cast(float, (unsigned)u.us[4] << 16);
                f1.y = __builtin_bit_cast(float, (unsigned)u.us[5] << 16);
                f1.z = __builtin_bit_cast(float, (unsigned)u.us[6] << 16);
                f1.w = __builtin_bit_cast(float, (unsigned)u.us[7] << 16);
            }
            const int row = f >> 9, col = f & 511;
            *reinterpret_cast<float4*>(&nrm[row][col])     = f0;
            *reinterpret_cast<float4*>(&nrm[row][col + 4]) = f1;
        }
    }

    __syncthreads();   // drains vmcnt (global_load_lds) + lgkm

    // ---- compute: wave w owns ksteps s = w*16 .. w*16+15 ----
    f32x4 acc0 = {0.f, 0.f, 0.f, 0.f};
    f32x4 acc1 = {0.f, 0.f, 0.f, 0.f};

    #pragma unroll 4
    for (int i = 0; i < 16; ++i) {
        const int s = w * 16 + i;
        const int g = s * 4 + q;

        const int qb = cl * QPITCH + g * 3;
        const unsigned d0 = qls[qb];
        const unsigned d1 = qls[qb + 1];
        const unsigned d2 = qls[qb + 2];
        const unsigned val = (d0 & 0xFFu) | ((d1 & 0xFFu) << 8) | ((d2 & 0xFFu) << 16);

        const float n  = nrm[cl][g];
        const float av = n * 0.285714285714285714f;   // 2n/7
        union { unsigned short us[8]; short8 v; } B;
        #pragma unroll
        for (int e = 0; e < 8; ++e) {
            const float qf = (float)((val >> (3 * e)) & 7u);
            B.us[e] = f2bf_u(fmaf(qf, av, -n));
        }

        const short8 A0 = *reinterpret_cast<const short8*>(&apk[(s * 64 + lane) * 8]);
        const short8 A1 = *reinterpret_cast<const short8*>(&apk[((128 + s) * 64 + lane) * 8]);

        acc0 = __builtin_amdgcn_mfma_f32_16x16x32_bf16(A0, B.v, acc0, 0, 0, 0);
        acc1 = __builtin_amdgcn_mfma_f32_16x16x32_bf16(A1, B.v, acc1, 0, 0, 0);
    }

    // ---- cross-wave K-reduction + bias + store ----
    #pragma unroll
    for (int i = 0; i < 4; ++i) {
        red[w][q * 4 + i][cl]      = acc0[i];
        red[w][16 + q * 4 + i][cl] = acc1[i];
    }
    __syncthreads();
    {
        const int m  = tid >> 4;   // 0..31
        const int nl = tid & 15;
        float ssum = 0.f;
        #pragma unroll
        for (int wv = 0; wv < NW; ++wv) ssum += red[wv][m][nl];
        out[m * OUT_F + nbase + nl] = ssum + bias[nbase + nl];
    }
}

__global__ __launch_bounds__(512, 2)
void l3b_main(const float* __restrict__ x, const int* __restrict__ wq3,
              const void* __restrict__ wn, const float* __restrict__ bias,
              float* __restrict__ out, const unsigned short* __restrict__ apk)
{
    __shared__ unsigned int qls[BN * QPITCH];
    __shared__ float        nrm[BN][NPITCH];
    __shared__ float        red[NW][BATCH][17];
    l3b_body(x, wq3, wn, bias, out, apk, qls, nrm, red);
}

// single cooperative dispatch: pack phase -> grid sync -> main phase
__global__ __launch_bounds__(512, 2)
void l3b_coop(const float* __restrict__ x, const int* __restrict__ wq3,
              const void* __restrict__ wn, const float* __restrict__ bias,
              float* __restrict__ out, unsigned short* __restrict__ apk)
{
    __shared__ unsigned int qls[BN * QPITCH];
    __shared__ float        nrm[BN][NPITCH];
    __shared__ float        red[NW][BATCH][17];

    if (threadIdx.x < 64)
        pack_unit(x, apk, blockIdx.x * 64 + threadIdx.x);   // 256*64 = 16384 units
    __threadfence();
    cg::this_grid().sync();

    l3b_body(x, wq3, wn, bias, out, apk, qls, nrm, red);
}

extern "C" void kernel_launch(void* const* d_in, const int* in_sizes, int n_in,
                              void* d_out, int out_size, void* d_ws, size_t ws_size,
                              hipStream_t stream) {
    const float* x    = (const float*)d_in[0];
    const int*   wq3  = (const int*)d_in[1];
    const void*  wn   = (const void*)d_in[2];
    const float* bias = (const float*)d_in[3];
    float*       out  = (float*)d_out;
    unsigned short* apk = (unsigned short*)d_ws;   // 256 KB used

    void* args[] = {(void*)&x, (void*)&wq3, (void*)&wn, (void*)&bias,
                    (void*)&out, (void*)&apk};
    hipError_t e = hipLaunchCooperativeKernel((const void*)l3b_coop,
                                              dim3(OUT_F / BN), dim3(512),
                                              args, 0, stream);
    if (e != hipSuccess) {
        // fallback: proven 2-dispatch path (r7)
        pack_x_kernel<<<dim3(64), dim3(256), 0, stream>>>(x, apk);
        l3b_main<<<dim3(OUT_F / BN), dim3(512), 0, stream>>>(x, wq3, wn, bias, out, apk);
    }
}

// Round 10
// 17.455 us; speedup vs baseline: 5.0117x; 5.0117x over previous
//
#include <hip/hip_runtime.h>
#include <hip/hip_fp16.h>

#define IN_F   4096
#define OUT_F  4096
#define BATCH  32
#define NGPR   512          // groups per output row
#define BN     16           // output rows per block
#define NW     8            // waves per block
#define QPITCH 1540         // dwords per q-row in LDS (1536 + 4; 1540%32==4 -> 2-way banks)
#define NPITCH 516          // floats per norm-row in LDS (512 + 4)

typedef float f32x4  __attribute__((ext_vector_type(4)));
typedef short short8 __attribute__((ext_vector_type(8)));

__device__ __forceinline__ unsigned short f2bf_u(float f) {
    return __builtin_bit_cast(unsigned short, (__bf16)f);   // RNE via v_cvt
}

__device__ __forceinline__ void gload16(const void* gsrc, void* lds) {
    __builtin_amdgcn_global_load_lds(
        (const __attribute__((address_space(1))) void*)gsrc,
        (__attribute__((address_space(3))) void*)lds, 16, 0, 0);
}

// ---- pack x[32][4096] fp32 -> A-fragment-layout bf16 in d_ws ----
// apk unit u = (a*128 + s)*64 + q*16 + cl  holds bf16 x[a*16+cl][s*32+q*8 .. +8]
__global__ __launch_bounds__(256)
void pack_x_kernel(const float* __restrict__ x, unsigned short* __restrict__ apk)
{
    const int tau = blockIdx.x * 256 + threadIdx.x;   // 0..16383
    const int row = tau >> 9;                         // 0..31
    const int c   = tau & 511;                        // 8-float chunk within row
    const float4 lo = *reinterpret_cast<const float4*>(&x[row * IN_F + c * 8]);
    const float4 hi = *reinterpret_cast<const float4*>(&x[row * IN_F + c * 8 + 4]);
    union { unsigned short us[8]; uint4 v; } pk;
    pk.us[0] = f2bf_u(lo.x); pk.us[1] = f2bf_u(lo.y);
    pk.us[2] = f2bf_u(lo.z); pk.us[3] = f2bf_u(lo.w);
    pk.us[4] = f2bf_u(hi.x); pk.us[5] = f2bf_u(hi.y);
    pk.us[6] = f2bf_u(hi.z); pk.us[7] = f2bf_u(hi.w);
    const int a = row >> 4, cl = row & 15, s = c >> 2, q = c & 3;
    const int unit = (a * 128 + s) * 64 + q * 16 + cl;
    *reinterpret_cast<uint4*>(&apk[unit * 8]) = pk.v;
}

__global__ __launch_bounds__(512, 2)
void l3b_main(const float* __restrict__ x,
              const int* __restrict__ wq3,
              const void* __restrict__ wnorm_raw,
              const float* __restrict__ bias,
              float* __restrict__ out,
              const unsigned short* __restrict__ apk)
{
    __shared__ unsigned int qls[BN * QPITCH];   // raw q dwords, ~96 KB
    __shared__ float        nrm[BN][NPITCH];    // fp32 scales, 33 KB
    __shared__ float        red[NW][BATCH][17]; // 17.4 KB

    const int tid   = threadIdx.x;
    const int w     = tid >> 6;
    const int lane  = tid & 63;
    const int nbase = blockIdx.x * BN;

    const int q  = lane >> 4;   // 0..3
    const int cl = lane & 15;   // 0..15

    // ---- weight_norm dtype probe (deterministic, wave-uniform) ----
    // 0 = float32, 1 = float16 (raw), 2 = bfloat16
    const unsigned short* wn16  = (const unsigned short*)wnorm_raw;
    const float*          wn32  = (const float*)wnorm_raw;
    const unsigned int*   wnu32 = (const unsigned int*)wnorm_raw;
    int mode;
    {
        const unsigned short h = wn16[lane];
        const float v16 = __half2float(__builtin_bit_cast(__half, h));
        const float vbf = __builtin_bit_cast(float, (unsigned int)h << 16);
        const float v32 = wn32[lane];
        const int c16 = __popcll(__ballot(v16 > 0.0095f && v16 < 1.0005f));
        const int cbf = __popcll(__ballot(vbf > 0.0095f && vbf < 1.0005f));
        const int c32 = __popcll(__ballot(v32 > 0.0095f && v32 < 1.0005f));
        if (c16 >= c32 && c16 >= cbf) {
            mode = 1;
        } else if (c32 > cbf + 8) {
            mode = 0;
        } else if (cbf > c32 + 8) {
            mode = 2;
        } else {
            const int z = __popcll(__ballot((wnu32[lane] & 0x1FFFu) == 0u));
            mode = (z >= 48) ? 0 : 2;
        }
    }

    const int* qg = wq3 + (long)nbase * 1536;

    // ---- section A: issue q chunk0 (rows 2w,2w+1; dword cols [0,768)) ----
    #pragma unroll
    for (int rr = 0; rr < 2; ++rr) {
        const int row = w * 2 + rr;
        #pragma unroll
        for (int i = 0; i < 3; ++i) {
            const int off = i * 256 + lane * 4;
            gload16(qg + (long)row * 1536 + off, &qls[row * QPITCH + off]);
        }
    }
    __builtin_amdgcn_sched_barrier(0);

    // ---- section B: issue norm loads -> VGPRs ----
    uint4 nraw[4];
    if (mode == 0) {
        const float* nb = wn32 + (long)nbase * NGPR;
        #pragma unroll
        for (int j = 0; j < 4; ++j)
            nraw[j] = *reinterpret_cast<const uint4*>(nb + j * 2048 + tid * 4);
    } else {
        const unsigned short* nb = wn16 + (long)nbase * NGPR;
        #pragma unroll
        for (int j = 0; j < 2; ++j)
            nraw[j] = *reinterpret_cast<const uint4*>(nb + j * 4096 + tid * 8);
    }
    __builtin_amdgcn_sched_barrier(0);

    // ---- section C: issue q chunk1 (cols [768,1536)) ----
    #pragma unroll
    for (int rr = 0; rr < 2; ++rr) {
        const int row = w * 2 + rr;
        #pragma unroll
        for (int i = 3; i < 6; ++i) {
            const int off = i * 256 + lane * 4;
            gload16(qg + (long)row * 1536 + off, &qls[row * QPITCH + off]);
        }
    }
    __builtin_amdgcn_sched_barrier(0);

    // ---- section D: wait c0+norms (c1 stays in flight); write nrm; barrier ----
    asm volatile("s_waitcnt vmcnt(6)" ::: "memory");
    __builtin_amdgcn_sched_barrier(0);
    if (mode == 0) {
        #pragma unroll
        for (int j = 0; j < 4; ++j) {
            const int f = j * 2048 + tid * 4;
            *reinterpret_cast<uint4*>(&nrm[f >> 9][f & 511]) = nraw[j];
        }
    } else {
        #pragma unroll
        for (int j = 0; j < 2; ++j) {
            const int f = j * 4096 + tid * 8;
            union { unsigned short us[8]; uint4 v; } u;
            u.v = nraw[j];
            float4 f0, f1;
            if (mode == 1) {
                f0.x = __half2float(__builtin_bit_cast(__half, u.us[0]));
                f0.y = __half2float(__builtin_bit_cast(__half, u.us[1]));
                f0.z = __half2float(__builtin_bit_cast(__half, u.us[2]));
                f0.w = __half2float(__builtin_bit_cast(__half, u.us[3]));
                f1.x = __half2float(__builtin_bit_cast(__half, u.us[4]));
                f1.y = __half2float(__builtin_bit_cast(__half, u.us[5]));
                f1.z = __half2float(__builtin_bit_cast(__half, u.us[6]));
                f1.w = __half2float(__builtin_bit_cast(__half, u.us[7]));
            } else {
                f0.x = __builtin_bit_cast(float, (unsigned)u.us[0] << 16);
                f0.y = __builtin_bit_cast(float, (unsigned)u.us[1] << 16);
                f0.z = __builtin_bit_cast(float, (unsigned)u.us[2] << 16);
                f0.w = __builtin_bit_cast(float, (unsigned)u.us[3] << 16);
                f1.x = __builtin_bit_cast(float, (unsigned)u.us[4] << 16);
                f1.y = __builtin_bit_cast(float, (unsigned)u.us[5] << 16);
                f1.z = __builtin_bit_cast(float, (unsigned)u.us[6] << 16);
                f1.w = __builtin_bit_cast(float, (unsigned)u.us[7] << 16);
            }
            const int row = f >> 9, col = f & 511;
            *reinterpret_cast<float4*>(&nrm[row][col])     = f0;
            *reinterpret_cast<float4*>(&nrm[row][col + 4]) = f1;
        }
    }
    asm volatile("s_waitcnt lgkmcnt(0)" ::: "memory");
    __builtin_amdgcn_s_barrier();
    __builtin_amdgcn_sched_barrier(0);

    // ---- compute: one K-step (group g = s*4+q, row cl) ----
    f32x4 acc0 = {0.f, 0.f, 0.f, 0.f};
    f32x4 acc1 = {0.f, 0.f, 0.f, 0.f};

    auto body = [&](int s) {
        const int g = s * 4 + q;

        const int qb = cl * QPITCH + g * 3;
        const unsigned d0 = qls[qb];
        const unsigned d1 = qls[qb + 1];
        const unsigned d2 = qls[qb + 2];
        const unsigned val = (d0 & 0xFFu) | ((d1 & 0xFFu) << 8) | ((d2 & 0xFFu) << 16);

        const float n  = nrm[cl][g];
        const float av = n * 0.285714285714285714f;   // 2n/7
        union { unsigned short us[8]; short8 v; } B;
        #pragma unroll
        for (int e = 0; e < 8; ++e) {
            const float qf = (float)((val >> (3 * e)) & 7u);
            B.us[e] = f2bf_u(fmaf(qf, av, -n));
        }

        const short8 A0 = *reinterpret_cast<const short8*>(&apk[(s * 64 + lane) * 8]);
        const short8 A1 = *reinterpret_cast<const short8*>(&apk[((128 + s) * 64 + lane) * 8]);

        acc0 = __builtin_amdgcn_mfma_f32_16x16x32_bf16(A0, B.v, acc0, 0, 0, 0);
        acc1 = __builtin_amdgcn_mfma_f32_16x16x32_bf16(A1, B.v, acc1, 0, 0, 0);
    };

    // ---- section E: compute chunk0 (s in [w*8, w*8+8) -> cols < 768) ----
    #pragma unroll
    for (int i = 0; i < 8; ++i) body(w * 8 + i);

    // ---- section F: drain c1 (all waves), barrier ----
    asm volatile("s_waitcnt vmcnt(0)" ::: "memory");
    __builtin_amdgcn_s_barrier();
    __builtin_amdgcn_sched_barrier(0);

    // ---- section G: compute chunk1 (s in [64+w*8, 64+w*8+8)) ----
    #pragma unroll
    for (int i = 0; i < 8; ++i) body(64 + w * 8 + i);

    // ---- cross-wave K-reduction + bias + store ----
    #pragma unroll
    for (int i = 0; i < 4; ++i) {
        red[w][q * 4 + i][cl]      = acc0[i];
        red[w][16 + q * 4 + i][cl] = acc1[i];
    }
    __syncthreads();
    {
        const int m  = tid >> 4;   // 0..31
        const int nl = tid & 15;
        float ssum = 0.f;
        #pragma unroll
        for (int wv = 0; wv < NW; ++wv) ssum += red[wv][m][nl];
        out[m * OUT_F + nbase + nl] = ssum + bias[nbase + nl];
    }
}

extern "C" void kernel_launch(void* const* d_in, const int* in_sizes, int n_in,
                              void* d_out, int out_size, void* d_ws, size_t ws_size,
                              hipStream_t stream) {
    const float* x    = (const float*)d_in[0];
    const int*   wq3  = (const int*)d_in[1];
    const void*  wn   = (const void*)d_in[2];
    const float* bias = (const float*)d_in[3];
    float*       out  = (float*)d_out;
    unsigned short* apk = (unsigned short*)d_ws;   // 256 KB used

    pack_x_kernel<<<dim3(64), dim3(256), 0, stream>>>(x, apk);
    l3b_main<<<dim3(OUT_F / BN), dim3(512), 0, stream>>>(x, wq3, wn, bias, out, apk);
}